// Round 1
// baseline (127.169 us; speedup 1.0000x reference)
//
#include <hip/hip_runtime.h>
#include <math.h>

#define RES 96
#define NPTS (RES * RES * RES)   // 884736
#define BLK  256
#define NBLK (NPTS / BLK)        // 3456 (exact)

struct BH {
    float bx0, by0, bz0, bx1, by1, bz1, hm0, hm1; // hm = softplus(m_pre)/2
};

// x = linspace(DX*(1-48), DX*(48-1), 96), DX = 1/47  ->  [-1, 1], step 2/95
__device__ __forceinline__ float lin_coord(int t) {
    const float DXc   = 1.0f / 47.0f;
    const float start = -47.0f * DXc;
    const float stop  =  47.0f * DXc;
    const float step  = (stop - start) / 95.0f;
    return fmaf((float)t, step, start);
}

// f = psi^4, psi = 1 + hm0/r0 + hm1/r1
// meshgrid 'xy': X varies along array axis 1, Y along axis 0, Z along axis 2
__device__ __forceinline__ float psi4_at(int a0, int a1, int a2, const BH& b) {
    float cx = lin_coord(a1);
    float cy = lin_coord(a0);
    float cz = lin_coord(a2);
    float dx0 = cx - b.bx0, dy0 = cy - b.by0, dz0 = cz - b.bz0;
    float dx1 = cx - b.bx1, dy1 = cy - b.by1, dz1 = cz - b.bz1;
    float r0 = sqrtf(dx0 * dx0 + dy0 * dy0 + dz0 * dz0);
    float r1 = sqrtf(dx1 * dx1 + dy1 * dy1 + dz1 * dz1);
    float psi = 1.0f + b.hm0 / r0 + b.hm1 / r1;
    float p2 = psi * psi;
    return p2 * p2;
}

// Gamma^i_{jk} = 0.5*psi^-4 * (d_ij D_k + d_ik D_j - d_jk D_i) = G-triple expansion.
__global__ __launch_bounds__(BLK) void gamma_kernel(
        const float* __restrict__ bh_pos,    // [2,3] row-major
        const float* __restrict__ bh_mpre,   // [2]
        float* __restrict__ out)             // [96,96,96,3,3,3]
{
    __shared__ float Gs[BLK * 3];
    const int tid = threadIdx.x;
    const int p   = blockIdx.x * BLK + tid;   // flat grid-point index
    int a2 = p % RES;
    int t  = p / RES;
    int a1 = t % RES;
    int a0 = t / RES;

    BH b;
    b.bx0 = bh_pos[0]; b.by0 = bh_pos[1]; b.bz0 = bh_pos[2];
    b.bx1 = bh_pos[3]; b.by1 = bh_pos[4]; b.bz1 = bh_pos[5];
    b.hm0 = 0.5f * log1pf(expf(bh_mpre[0]));  // softplus, m_pre in [0,1] -> safe
    b.hm1 = 0.5f * log1pf(expf(bh_mpre[1]));

    const float DXc = 1.0f / 47.0f;  // gradient spacing per reference (NOT the true grid step)
    float fc = psi4_at(a0, a1, a2, b);

    // np.gradient edge_order=1: interior (f[a+1]-f[a-1])/(2DX), edges one-sided /DX.
    // Unified via clamped indices: D = (f(ap)-f(am)) / ((ap-am)*DX).
    int a0m = a0 > 0 ? a0 - 1 : 0, a0p = a0 < RES - 1 ? a0 + 1 : RES - 1;
    int a1m = a1 > 0 ? a1 - 1 : 0, a1p = a1 < RES - 1 ? a1 + 1 : RES - 1;
    int a2m = a2 > 0 ? a2 - 1 : 0, a2p = a2 < RES - 1 ? a2 + 1 : RES - 1;

    float D0 = (psi4_at(a0p, a1, a2, b) - psi4_at(a0m, a1, a2, b)) / ((float)(a0p - a0m) * DXc);
    float D1 = (psi4_at(a0, a1p, a2, b) - psi4_at(a0, a1m, a2, b)) / ((float)(a1p - a1m) * DXc);
    float D2 = (psi4_at(a0, a1, a2p, b) - psi4_at(a0, a1, a2m, b)) / ((float)(a2p - a2m) * DXc);

    float E = 0.5f / fc;
    // stride-3 LDS writes: gcd(3,32)=1 -> conflict-free
    Gs[tid * 3 + 0] = E * D0;
    Gs[tid * 3 + 1] = E * D1;
    Gs[tid * 3 + 2] = E * D2;
    __syncthreads();

    // Cooperative coalesced write of this block's 256*27 contiguous outputs.
    float* oblk = out + (size_t)blockIdx.x * (BLK * 27);
#pragma unroll
    for (int w = 0; w < 27; ++w) {
        int e  = w * BLK + tid;      // consecutive lanes -> consecutive floats
        int pl = e / 27;             // local point
        int c  = e - pl * 27;        // component i*9+j*3+k
        int i  = c / 9;
        int r  = c - 9 * i;
        int j  = r / 3;
        int k  = r - 3 * j;
        float v = 0.0f;
        if (i == j) v += Gs[pl * 3 + k];
        if (i == k) v += Gs[pl * 3 + j];
        if (j == k) v -= Gs[pl * 3 + i];
        oblk[e] = v;
    }
}

extern "C" void kernel_launch(void* const* d_in, const int* in_sizes, int n_in,
                              void* d_out, int out_size, void* d_ws, size_t ws_size,
                              hipStream_t stream) {
    const float* bh_pos  = (const float*)d_in[0];  // BH_positions [2,3]
    const float* bh_mpre = (const float*)d_in[1];  // BH_masses_presoftplus [2]
    float* out = (float*)d_out;                    // fp32 output, 96^3*27 elements
    gamma_kernel<<<NBLK, BLK, 0, stream>>>(bh_pos, bh_mpre, out);
}

// Round 2
// 103.480 us; speedup vs baseline: 1.2289x; 1.2289x over previous
//
#include <hip/hip_runtime.h>
#include <math.h>

#define RES 96
#define NPTS (RES * RES * RES)   // 884736
#define BLK  256
#define NBLK (NPTS / BLK)        // 3456 (exact)
#define F4_PER_BLK (BLK * 27 / 4)  // 1728 float4 per block (BLK*27 divisible by 4)

struct BH {
    float bx0, by0, bz0, bx1, by1, bz1, hm0, hm1; // hm = softplus(m_pre)/2
};

// x = linspace(DX*(1-48), DX*(48-1), 96), DX = 1/47  ->  [-1, 1], step 2/95
__device__ __forceinline__ float lin_coord(int t) {
    const float DXc   = 1.0f / 47.0f;
    const float start = -47.0f * DXc;
    const float stop  =  47.0f * DXc;
    const float step  = (stop - start) / 95.0f;
    return fmaf((float)t, step, start);
}

// f = psi^4, psi = 1 + hm0/r0 + hm1/r1.  1/r via v_rsq_f32 (approx ~1ulp —
// absmax threshold 116.5, observed 0.06: huge slack).
// meshgrid 'xy': X varies along array axis 1, Y along axis 0, Z along axis 2.
__device__ __forceinline__ float psi4_at(int a0, int a1, int a2, const BH& b) {
    float cx = lin_coord(a1);
    float cy = lin_coord(a0);
    float cz = lin_coord(a2);
    float dx0 = cx - b.bx0, dy0 = cy - b.by0, dz0 = cz - b.bz0;
    float dx1 = cx - b.bx1, dy1 = cy - b.by1, dz1 = cz - b.bz1;
    float dd0 = fmaf(dx0, dx0, fmaf(dy0, dy0, dz0 * dz0));
    float dd1 = fmaf(dx1, dx1, fmaf(dy1, dy1, dz1 * dz1));
    float psi = 1.0f + fmaf(b.hm0, __builtin_amdgcn_rsqf(dd0),
                            b.hm1 * __builtin_amdgcn_rsqf(dd1));
    float p2 = psi * psi;
    return p2 * p2;
}

// Gamma^i_{jk} = 0.5*psi^-4 * (d_ij D_k + d_ik D_j - d_jk D_i):
// only 3 scalars G_c per point; the 27 outputs are a fixed +-G/0 pattern.
__global__ __launch_bounds__(BLK) void gamma_kernel(
        const float* __restrict__ bh_pos,    // [2,3] row-major
        const float* __restrict__ bh_mpre,   // [2]
        float* __restrict__ out)             // [96,96,96,3,3,3]
{
    __shared__ __align__(16) float Gs27[BLK * 27];  // 27 KB: full per-point pattern
    const int tid = threadIdx.x;
    const int p   = blockIdx.x * BLK + tid;   // flat grid-point index
    int a2 = p % RES;
    int t  = p / RES;
    int a1 = t % RES;
    int a0 = t / RES;

    BH b;
    b.bx0 = bh_pos[0]; b.by0 = bh_pos[1]; b.bz0 = bh_pos[2];
    b.bx1 = bh_pos[3]; b.by1 = bh_pos[4]; b.bz1 = bh_pos[5];
    b.hm0 = 0.5f * log1pf(expf(bh_mpre[0]));  // softplus, m_pre in [0,1] -> safe
    b.hm1 = 0.5f * log1pf(expf(bh_mpre[1]));

    float fc = psi4_at(a0, a1, a2, b);

    // np.gradient edge_order=1 via clamped indices: D = (f(ap)-f(am)) * scale,
    // scale = 1/((ap-am)*DX): interior 47/2, edges 47.  Multiply, don't divide.
    int a0m = a0 > 0 ? a0 - 1 : 0, a0p = a0 < RES - 1 ? a0 + 1 : RES - 1;
    int a1m = a1 > 0 ? a1 - 1 : 0, a1p = a1 < RES - 1 ? a1 + 1 : RES - 1;
    int a2m = a2 > 0 ? a2 - 1 : 0, a2p = a2 < RES - 1 ? a2 + 1 : RES - 1;
    float s0 = (a0p - a0m == 2) ? 23.5f : 47.0f;
    float s1 = (a1p - a1m == 2) ? 23.5f : 47.0f;
    float s2 = (a2p - a2m == 2) ? 23.5f : 47.0f;

    float D0 = (psi4_at(a0p, a1, a2, b) - psi4_at(a0m, a1, a2, b)) * s0;
    float D1 = (psi4_at(a0, a1p, a2, b) - psi4_at(a0, a1m, a2, b)) * s1;
    float D2 = (psi4_at(a0, a1, a2p, b) - psi4_at(a0, a1, a2m, b)) * s2;

    float E = 0.5f * __builtin_amdgcn_rcpf(fc);
    float G0 = E * D0, G1 = E * D1, G2 = E * D2;

    // Expand the fixed pattern into LDS (stride 27, gcd(27,32)=1: conflict-free).
    // i==j==k -> G_i; i==j!=k -> G_k; i==k!=j -> G_j; j==k!=i -> -G_i; else 0.
    // Compile-time i,j,k fold each v to a plain +-G / 0 write.
    float G[3] = {G0, G1, G2};
    float* myg = Gs27 + tid * 27;
#pragma unroll
    for (int c = 0; c < 27; ++c) {
        const int i = c / 9, j = (c / 3) % 3, k = c % 3;
        float v = 0.0f;
        if (i == j) v += G[k];
        if (i == k) v += G[j];
        if (j == k) v -= G[i];
        myg[c] = v;
    }
    __syncthreads();

    // Stream the block's 27648 contiguous bytes with float4 (ds_read_b128 +
    // global_store_dwordx4).  1728 float4 / 256 threads = 7 iters, last partial.
    const float4* src = (const float4*)Gs27;
    float4* dst = (float4*)(out + (size_t)blockIdx.x * (BLK * 27));
#pragma unroll
    for (int w = 0; w < 7; ++w) {
        int q = w * BLK + tid;
        if (q < F4_PER_BLK) dst[q] = src[q];
    }
}

extern "C" void kernel_launch(void* const* d_in, const int* in_sizes, int n_in,
                              void* d_out, int out_size, void* d_ws, size_t ws_size,
                              hipStream_t stream) {
    const float* bh_pos  = (const float*)d_in[0];  // BH_positions [2,3]
    const float* bh_mpre = (const float*)d_in[1];  // BH_masses_presoftplus [2]
    float* out = (float*)d_out;                    // fp32 output, 96^3*27 elements
    gamma_kernel<<<NBLK, BLK, 0, stream>>>(bh_pos, bh_mpre, out);
}